// Round 6
// baseline (233.516 us; speedup 1.0000x reference)
//
#include <hip/hip_runtime.h>
#include <stdint.h>

// net_71322226917474: 2-layer GNN (SAGE-like) on MI355X.
// dst = repeat(arange(N),16) -> edges of node j are j*16..j*16+15, deg==16.
// bf16 matmul path (threshold 0.645), f32 accumulate.
// R6: R5 (global_load_lds DMA gather, counted vmcnt) + WAR-hazard fix:
//     drain lgkmcnt before each DMA batch so the LDS-DMA write cannot land
//     while the previous iteration's ds_reads of that buffer are in flight.

#define N_NODES 100000
#define DEG 16
#define F 128
#define K2 256
#define TILE 32     // rows per block; 100000 = 3125 * 32 exactly
#define LDP 264     // padded sIn row stride (halves)

typedef __attribute__((ext_vector_type(8))) short short8;
typedef __attribute__((ext_vector_type(4))) float f32x4;
typedef __attribute__((ext_vector_type(4))) unsigned short us4;

__device__ __forceinline__ unsigned short f2bf(float f) {
    unsigned u = __builtin_bit_cast(unsigned, f);
    u += 0x7FFFu + ((u >> 16) & 1u);   // RNE
    return (unsigned short)(u >> 16);
}
__device__ __forceinline__ float bf2f(unsigned short h) {
    return __builtin_bit_cast(float, (unsigned)h << 16);
}

// async global->LDS, 16B per lane; LDS dest = wave-uniform base + lane*16
__device__ __forceinline__ void dma16(const unsigned short* g, unsigned short* l) {
    __builtin_amdgcn_global_load_lds(
        (const __attribute__((address_space(1))) unsigned int*)(const void*)g,
        (__attribute__((address_space(3))) unsigned int*)(void*)l,
        16, 0, 0);
}

// ---- prep: x (f32) -> xb (bf16) ----
__global__ void cast_x_kernel(const float* __restrict__ x, unsigned short* __restrict__ xb) {
    int i = blockIdx.x * blockDim.x + threadIdx.x;
    const float4 v = ((const float4*)x)[i];
    us4 o; o.x = f2bf(v.x); o.y = f2bf(v.y); o.z = f2bf(v.z); o.w = f2bf(v.w);
    ((us4*)xb)[i] = o;
}

// ---- prep: Bt[layer][n][k] = bf16( k<128 ? W[n][k] : Wr[n][k-128] ) ----
__global__ void build_bt_kernel(const float* __restrict__ W0, const float* __restrict__ Wr0,
                                const float* __restrict__ W1, const float* __restrict__ Wr1,
                                unsigned short* __restrict__ Bt) {
    int t = blockIdx.x * 256 + threadIdx.x;
    int layer = t >> 15;
    int n = (t >> 8) & 127;
    int k = t & 255;
    const float* W  = layer ? W1  : W0;
    const float* Wr = layer ? Wr1 : Wr0;
    float v = (k < 128) ? W[n * 128 + k] : Wr[n * 128 + (k - 128)];
    Bt[t] = f2bf(v);
}

// ---- one layer ----
__global__ __launch_bounds__(256, 3) void layer_kernel(
    const unsigned short* __restrict__ hb,   // [N][128] bf16 input
    const unsigned short* __restrict__ Bt,   // [128][256] bf16 combined weights
    const float* __restrict__ bias,          // [128] f32
    const int* __restrict__ src,             // [E] edge sources
    unsigned short* __restrict__ outb,       // bf16 out (layer 0) or null
    float* __restrict__ outf)                // f32 out (layer 1) or null
{
    __shared__ unsigned short sIn[TILE][LDP];       // [row][0:128)=agg, [128:256)=h
    __shared__ unsigned short sStage[4][2][2048];   // [wave][buf][16 src rows * 128 halves]
    const int tid = threadIdx.x;
    const int w = tid >> 6, ln = tid & 63;
    const int r0 = blockIdx.x * TILE;
    const int rw = r0 + w * 8;                      // wave's first global row

    // ---- own-row h -> second K-half of sIn ----
    #pragma unroll
    for (int i = 0; i < 4; ++i) {
        const int tr = w * 8 + 2 * i + (ln >> 5);
        const us4 v = *(const us4*)(hb + (size_t)(r0 + tr) * F + (ln & 31) * 4);
        *(us4*)&sIn[tr][128 + (ln & 31) * 4] = v;
    }

    // ---- precompute all 32 dma element-offsets (8 rows x 4 batches) ----
    // dma instr (row r, batch b): lane l fetches 16B of src row
    // su[r][b*4 + (l>>4)] at halves (l&15)*8.
    int off[32];
    {
        int su[8];
        #pragma unroll
        for (int r = 0; r < 8; ++r) su[r] = src[(rw + r) * DEG + (ln & 15)];
        #pragma unroll
        for (int r = 0; r < 8; ++r) {
            #pragma unroll
            for (int b = 0; b < 4; ++b) {
                const int idx = __shfl(su[r], b * 4 + (ln >> 4));
                off[r * 4 + b] = idx * F + (ln & 15) * 8;    // halves
            }
        }
    }

    // ---- pipelined DMA gather: stage row r+1 while reducing row r ----
    #pragma unroll
    for (int b = 0; b < 4; ++b)
        dma16(hb + off[b], &sStage[w][0][b * 512]);

    #pragma unroll
    for (int r = 0; r < 8; ++r) {
        // WAR guard (the R5 bug): buffer (r+1)&1 is about to be overwritten by
        // DMA, but iteration r-1's reduce read it and those ds_reads may still
        // be in flight — the LDS-DMA write is NOT ordered against them. Drain
        // lgkm before issuing the overwriting DMAs.
        asm volatile("s_waitcnt lgkmcnt(0)" ::: "memory");
        __builtin_amdgcn_sched_barrier(0);
        if (r < 7) {
            const int p = (r + 1) & 1;
            #pragma unroll
            for (int b = 0; b < 4; ++b)
                dma16(hb + off[(r + 1) * 4 + b], &sStage[w][p][b * 512]);
            asm volatile("s_waitcnt vmcnt(4)" ::: "memory");
        } else {
            asm volatile("s_waitcnt vmcnt(0) lgkmcnt(0)" ::: "memory");
        }
        __builtin_amdgcn_sched_barrier(0);
        // reduce 16 staged rows -> agg halves 2*ln, 2*ln+1
        const unsigned* st = (const unsigned*)&sStage[w][r & 1][0];
        float s0 = 0.f, s1 = 0.f;
        #pragma unroll
        for (int s = 0; s < 16; ++s) {
            const unsigned pv = st[s * 64 + ln];
            s0 += bf2f((unsigned short)(pv & 0xffffu));
            s1 += bf2f((unsigned short)(pv >> 16));
        }
        const unsigned ov = (unsigned)f2bf(s0) | ((unsigned)f2bf(s1) << 16);
        *(unsigned*)&sIn[w * 8 + r][ln * 2] = ov;
    }
    __syncthreads();

    // ---- MFMA stage: wave w -> row-tile (w>>1), col-fragments (w&1)*4 .. +3 ----
    const int lc = ln & 15;
    const int kb = (ln >> 4) * 8;
    const int rt = w >> 1;
    const int cfb = (w & 1) * 4;
    f32x4 acc[4];
    #pragma unroll
    for (int cf = 0; cf < 4; ++cf) acc[cf] = (f32x4){0.f, 0.f, 0.f, 0.f};

    #pragma unroll
    for (int ks = 0; ks < 8; ++ks) {
        short8 af = *(const short8*)&sIn[rt * 16 + lc][ks * 32 + kb];
        #pragma unroll
        for (int cf = 0; cf < 4; ++cf) {
            short8 bfr = *(const short8*)(Bt + (size_t)((cfb + cf) * 16 + lc) * K2 + ks * 32 + kb);
            acc[cf] = __builtin_amdgcn_mfma_f32_16x16x32_bf16(af, bfr, acc[cf], 0, 0, 0);
        }
    }

    // ---- epilogue: out = relu(acc + b) - agg/16 ----
    const int rbase = (ln >> 4) * 4;   // C/D: col=lane&15, row=(lane>>4)*4+reg
    #pragma unroll
    for (int cf = 0; cf < 4; ++cf) {
        const int col = (cfb + cf) * 16 + lc;
        const float bv = bias[col];
        #pragma unroll
        for (int j = 0; j < 4; ++j) {
            const int trow = rt * 16 + rbase + j;
            const int grow = r0 + trow;
            float v = fmaxf(acc[cf][j] + bv, 0.f) - bf2f(sIn[trow][col]) * (1.0f / DEG);
            if (outb) outb[(size_t)grow * F + col] = f2bf(v);
            else      outf[(size_t)grow * F + col] = v;
        }
    }
}

extern "C" void kernel_launch(void* const* d_in, const int* in_sizes, int n_in,
                              void* d_out, int out_size, void* d_ws, size_t ws_size,
                              hipStream_t stream) {
    const float* x   = (const float*)d_in[0];
    const int*   ei  = (const int*)d_in[1];    // [2,E] row-major: src first
    const float* W0  = (const float*)d_in[2];
    const float* b0  = (const float*)d_in[3];
    const float* Wr0 = (const float*)d_in[4];
    const float* W1  = (const float*)d_in[5];
    const float* b1  = (const float*)d_in[6];
    const float* Wr1 = (const float*)d_in[7];
    const int* src = ei;                        // first E entries

    // workspace layout: xb 25.6MB | h1b 25.6MB | Bt 128KB
    unsigned short* xb  = (unsigned short*)d_ws;
    unsigned short* h1b = xb  + (size_t)N_NODES * F;
    unsigned short* Bt  = h1b + (size_t)N_NODES * F;

    cast_x_kernel<<<(N_NODES * F / 4 + 255) / 256, 256, 0, stream>>>(x, xb);
    build_bt_kernel<<<256, 256, 0, stream>>>(W0, Wr0, W1, Wr1, Bt);

    const int nb = N_NODES / TILE;   // 3125
    layer_kernel<<<nb, 256, 0, stream>>>(xb,  Bt,         b0, src, h1b,    nullptr);
    layer_kernel<<<nb, 256, 0, stream>>>(h1b, Bt + 32768, b1, src, nullptr, (float*)d_out);
}